// Round 4
// baseline (103.750 us; speedup 1.0000x reference)
//
#include <hip/hip_runtime.h>

// Neo-Hookean constants (match reference)
#define MU_C   3846.1538461538462f   // E/(2(1+nu))
#define LM_C   5769.2307692307695f   // E*nu/((1+nu)(1-2nu))
#define LOGC   (MU_C + 0.5f * LM_C)  // combined log coefficient
#define EPS_C  1e-10f

// B=4, N_QUAD=4, NPE=4 fixed by the reference problem.
#define ELB 256         // elements per block == threads per block (1 thread : 1 element)

// Transpose u (B, n_nodes, 3) -> ut (n_nodes, B, 4) padded float4 records (64B/node).
__global__ __launch_bounds__(256) void nh_transpose_u_pad(
    const float* __restrict__ u, float4* __restrict__ ut, int n_nodes)
{
    const int i = blockIdx.x * 256 + threadIdx.x;
    if (i >= n_nodes) return;
    float4* q = ut + (size_t)i * 4;
    #pragma unroll
    for (int b = 0; b < 4; ++b) {
        const float* p = u + ((size_t)b * n_nodes + i) * 3;
        q[b] = make_float4(p[0], p[1], p[2], 0.f);
    }
}

// One thread per element; thread computes all 4 batches.
__global__ __launch_bounds__(256) void nh_partial_v4(
    const float* __restrict__ u,          // (4, n_nodes, 3)  fallback
    const float4* __restrict__ ut,        // (n_nodes, 4) padded float4
    const int*   __restrict__ elements,   // (n_elem, 4)
    const float* __restrict__ dN_dx,      // (n_elem, 4, 4, 3)
    const float* __restrict__ detJ,       // (n_elem, 4)
    const float* __restrict__ qw,         // (4,)
    float* __restrict__ partial,          // (gridDim.x, 4)
    int n_elem, int n_nodes, int use_ut)
{
    // SoA: s_dn4[ch][el], ch = 0..11 (each ch is one float4 of the 48-float slab)
    __shared__ float4 s_dn4[12 * ELB];    // 48 KiB
    __shared__ float  s_red[4][4];

    const int t   = threadIdx.x;
    const int e0  = blockIdx.x * ELB;
    const int rem = min(ELB, n_elem - e0);

    // ---- stage dN_dx: 12 coalesced dwordx4 per thread, scatter to SoA ----
    {
        const float4* src = reinterpret_cast<const float4*>(dN_dx) + (size_t)e0 * 12;
        const int nf4 = rem * 12;
        #pragma unroll
        for (int j = 0; j < 12; ++j) {
            const int m = t + 256 * j;
            if (m < nf4) {
                const float4 v = src[m];
                s_dn4[(m % 12) * ELB + (m / 12)] = v;
            }
        }
    }
    __syncthreads();

    float acc[4] = {0.f, 0.f, 0.f, 0.f};

    if (t < rem) {
        const int e = e0 + t;
        // elements / detJ: lane==element -> naturally coalesced
        const int4 nd = reinterpret_cast<const int4*>(elements)[e];
        const int nodes[4] = {nd.x, nd.y, nd.z, nd.w};

        const float4 dj = reinterpret_cast<const float4*>(detJ)[e];
        const float4 w4 = *reinterpret_cast<const float4*>(qw);
        const float wq[4] = {dj.x * w4.x, dj.y * w4.y, dj.z * w4.z, dj.w * w4.w};

        // gather u for all 4 batches of the 4 nodes.
        // eu[n][b] = (x,y,z); with ut, node record = one 64B line, 4 dwordx4 (3 L1-hit)
        float eu[4][4][3];
        if (use_ut) {
            #pragma unroll
            for (int n = 0; n < 4; ++n) {
                const float4* p = ut + (size_t)nodes[n] * 4;
                #pragma unroll
                for (int b = 0; b < 4; ++b) {
                    const float4 v = p[b];
                    eu[n][b][0] = v.x; eu[n][b][1] = v.y; eu[n][b][2] = v.z;
                }
            }
        } else {
            #pragma unroll
            for (int n = 0; n < 4; ++n) {
                #pragma unroll
                for (int b = 0; b < 4; ++b) {
                    const float* p = u + ((size_t)b * n_nodes + nodes[n]) * 3;
                    eu[n][b][0] = p[0]; eu[n][b][1] = p[1]; eu[n][b][2] = p[2];
                }
            }
        }

        #pragma unroll
        for (int q = 0; q < 4; ++q) {
            // this q's 12 floats: three conflict-free ds_read_b128 (consecutive lanes)
            const float4 f0 = s_dn4[(q * 3 + 0) * ELB + t];
            const float4 f1 = s_dn4[(q * 3 + 1) * ELB + t];
            const float4 f2 = s_dn4[(q * 3 + 2) * ELB + t];
            const float d[12] = {f0.x, f0.y, f0.z, f0.w, f1.x, f1.y, f1.z, f1.w,
                                 f2.x, f2.y, f2.z, f2.w};
            // d[n*3 + j]

            #pragma unroll
            for (int b = 0; b < 4; ++b) {
                float F[3][3];
                #pragma unroll
                for (int i = 0; i < 3; ++i) {
                    #pragma unroll
                    for (int j = 0; j < 3; ++j) {
                        float g = 0.f;
                        #pragma unroll
                        for (int n = 0; n < 4; ++n)
                            g = fmaf(eu[n][b][i], d[n * 3 + j], g);
                        F[i][j] = g + ((i == j) ? 1.f : 0.f);
                    }
                }
                const float J =
                      F[0][0] * (F[1][1]*F[2][2] - F[1][2]*F[2][1])
                    - F[0][1] * (F[1][0]*F[2][2] - F[1][2]*F[2][0])
                    + F[0][2] * (F[1][0]*F[2][1] - F[1][1]*F[2][0]);

                float IC = 0.f;
                #pragma unroll
                for (int i = 0; i < 3; ++i)
                    #pragma unroll
                    for (int j = 0; j < 3; ++j)
                        IC = fmaf(F[i][j], F[i][j], IC);

                const float lj = __logf(fmaxf(J, EPS_C));
                const float W = 0.5f * MU_C * (IC - 3.f)
                              + 0.25f * LM_C * fmaf(J, J, -1.f)
                              - LOGC * lj;
                acc[b] = fmaf(W, wq[q], acc[b]);
            }
        }
    }

    // full-wave shuffle reduction per batch
    #pragma unroll
    for (int b = 0; b < 4; ++b) {
        float v = acc[b];
        #pragma unroll
        for (int off = 32; off > 0; off >>= 1)
            v += __shfl_down(v, off);
        acc[b] = v;   // lane 0 of each wave
    }

    const int lane = t & 63;
    const int wid  = t >> 6;
    if (lane == 0) {
        #pragma unroll
        for (int b = 0; b < 4; ++b) s_red[wid][b] = acc[b];
    }
    __syncthreads();
    if (t < 4)
        partial[(size_t)blockIdx.x * 4 + t] =
            (s_red[0][t] + s_red[1][t]) + (s_red[2][t] + s_red[3][t]);
}

__global__ __launch_bounds__(256) void nh_final(
    const float* __restrict__ partial,  // (nparts, 4)
    float* __restrict__ out,            // (4,)
    int nparts)
{
    float accb[4] = {0.f, 0.f, 0.f, 0.f};
    for (int i = threadIdx.x; i < nparts; i += 256) {
        const float4 p = reinterpret_cast<const float4*>(partial)[i];
        accb[0] += p.x; accb[1] += p.y; accb[2] += p.z; accb[3] += p.w;
    }

    #pragma unroll
    for (int b = 0; b < 4; ++b) {
        float v = accb[b];
        #pragma unroll
        for (int off = 32; off > 0; off >>= 1)
            v += __shfl_down(v, off);
        accb[b] = v;
    }

    __shared__ float lds[4][4];
    const int lane = threadIdx.x & 63;
    const int wid  = threadIdx.x >> 6;
    if (lane == 0) {
        #pragma unroll
        for (int b = 0; b < 4; ++b) lds[wid][b] = accb[b];
    }
    __syncthreads();
    if (threadIdx.x == 0) {
        #pragma unroll
        for (int b = 0; b < 4; ++b)
            out[b] = (lds[0][b] + lds[1][b]) + (lds[2][b] + lds[3][b]);
    }
}

extern "C" void kernel_launch(void* const* d_in, const int* in_sizes, int n_in,
                              void* d_out, int out_size, void* d_ws, size_t ws_size,
                              hipStream_t stream) {
    const float* u        = (const float*)d_in[0];
    const int*   elements = (const int*)d_in[1];
    const float* dN_dx    = (const float*)d_in[2];
    const float* detJ     = (const float*)d_in[3];
    const float* qw       = (const float*)d_in[4];
    float* out = (float*)d_out;

    const int B       = out_size;            // 4
    const int n_nodes = in_sizes[0] / (3 * B);
    const int n_elem  = in_sizes[1] / 4;

    const int threads = 256;
    const int nblocks = (n_elem + ELB - 1) / ELB;

    const size_t ut_bytes      = (size_t)n_nodes * 4 * sizeof(float4);  // padded
    const size_t partial_bytes = (size_t)nblocks * 4 * sizeof(float);
    const int use_ut = (ws_size >= ut_bytes + partial_bytes) ? 1 : 0;

    float4* ut     = (float4*)d_ws;
    float* partial = use_ut ? (float*)((char*)d_ws + ut_bytes) : (float*)d_ws;

    if (use_ut) {
        const int tb = (n_nodes + threads - 1) / threads;
        nh_transpose_u_pad<<<tb, threads, 0, stream>>>(u, ut, n_nodes);
    }

    nh_partial_v4<<<nblocks, threads, 0, stream>>>(u, ut, elements, dN_dx, detJ, qw,
                                                   partial, n_elem, n_nodes, use_ut);
    nh_final<<<1, threads, 0, stream>>>(partial, out, nblocks);
}

// Round 6
// 90.543 us; speedup vs baseline: 1.1459x; 1.1459x over previous
//
#include <hip/hip_runtime.h>

// Neo-Hookean constants (match reference)
#define MU_C   3846.1538461538462f   // E/(2(1+nu))
#define LM_C   5769.2307692307695f   // E*nu/((1+nu)(1-2nu))
#define LOGC   (MU_C + 0.5f * LM_C)  // combined log coefficient
#define EPS_C  1e-10f

// native vector types (required for __builtin_nontemporal_load)
typedef float nf4 __attribute__((ext_vector_type(4)));
typedef int   ni4 __attribute__((ext_vector_type(4)));

// B=4, N_QUAD=4, NPE=4 fixed by the reference problem.
// v5: thread = (element-pair, batch). Lanes 4p..4p+3 share element-indexed
// loads; each thread processes 2 elements to double memory-level parallelism.
#define EPB 128   // elements per block (256 threads, 2 elements/thread)

// Transpose u (B, n_nodes, 3) -> ut (n_nodes, B, 4) padded float4 (64B/node).
__global__ __launch_bounds__(256) void nh_transpose_u_pad(
    const float* __restrict__ u, float4* __restrict__ ut, int n_nodes)
{
    const int i = blockIdx.x * 256 + threadIdx.x;
    if (i >= n_nodes) return;
    float4* q = ut + (size_t)i * 4;
    #pragma unroll
    for (int b = 0; b < 4; ++b) {
        const float* p = u + ((size_t)b * n_nodes + i) * 3;
        q[b] = make_float4(p[0], p[1], p[2], 0.f);
    }
}

__device__ __forceinline__ float nh_energy_elem(
    const nf4* __restrict__ dv,    // 12 float4 = the element's dN slab
    const float eu[4][3],          // this batch's 4 node displacements
    const float wq[4])             // detJ*qw per quad point
{
    const float* d = reinterpret_cast<const float*>(dv);  // d[(q*4+n)*3+j]
    float a = 0.f;
    #pragma unroll
    for (int q = 0; q < 4; ++q) {
        float F[3][3];
        #pragma unroll
        for (int i = 0; i < 3; ++i) {
            #pragma unroll
            for (int j = 0; j < 3; ++j) {
                float g = 0.f;
                #pragma unroll
                for (int n = 0; n < 4; ++n)
                    g = fmaf(eu[n][i], d[(q*4 + n)*3 + j], g);
                F[i][j] = g + ((i == j) ? 1.f : 0.f);
            }
        }
        const float J =
              F[0][0] * (F[1][1]*F[2][2] - F[1][2]*F[2][1])
            - F[0][1] * (F[1][0]*F[2][2] - F[1][2]*F[2][0])
            + F[0][2] * (F[1][0]*F[2][1] - F[1][1]*F[2][0]);
        float IC = 0.f;
        #pragma unroll
        for (int i = 0; i < 3; ++i)
            #pragma unroll
            for (int j = 0; j < 3; ++j)
                IC = fmaf(F[i][j], F[i][j], IC);
        const float lj = __logf(fmaxf(J, EPS_C));
        const float W = 0.5f * MU_C * (IC - 3.f)
                      + 0.25f * LM_C * fmaf(J, J, -1.f)
                      - LOGC * lj;
        a = fmaf(W, wq[q], a);
    }
    return a;
}

__global__ __launch_bounds__(256) void nh_partial_v5(
    const float* __restrict__ u,          // (4, n_nodes, 3)  fallback
    const float4* __restrict__ ut,        // (n_nodes, 4) padded float4
    const int*   __restrict__ elements,   // (n_elem, 4)
    const float* __restrict__ dN_dx,      // (n_elem, 4, 4, 3)
    const float* __restrict__ detJ,       // (n_elem, 4)
    const float* __restrict__ qw,         // (4,)
    float* __restrict__ partial,          // (gridDim.x, 4)
    int n_elem, int n_nodes, int use_ut)
{
    const int t  = threadIdx.x;
    const int b  = t & 3;
    const int p  = t >> 2;                 // pair index within block
    const int e0 = blockIdx.x * EPB + p * 2;
    const int e1 = e0 + 1;
    const bool v0 = (e0 < n_elem);
    const bool v1 = (e1 < n_elem);

    const ni4* elp = reinterpret_cast<const ni4*>(elements);
    const nf4* djp = reinterpret_cast<const nf4*>(detJ);
    const nf4* dnp = reinterpret_cast<const nf4*>(dN_dx);

    float acc = 0.f;

    if (v0) {
        // ---- indices + detJ for both elements (issued together) ----
        ni4 nd0 = __builtin_nontemporal_load(elp + e0);
        ni4 nd1; nd1 = v1 ? __builtin_nontemporal_load(elp + e1) : nd0;
        nf4 dj0 = __builtin_nontemporal_load(djp + e0);
        nf4 dj1; dj1 = v1 ? __builtin_nontemporal_load(djp + e1) : dj0;

        // ---- dN slabs for both elements (24 independent loads) ----
        nf4 dv0[12], dv1[12];
        {
            const nf4* p0 = dnp + (size_t)e0 * 12;
            #pragma unroll
            for (int k = 0; k < 12; ++k) dv0[k] = __builtin_nontemporal_load(p0 + k);
            const nf4* p1 = dnp + (size_t)(v1 ? e1 : e0) * 12;
            #pragma unroll
            for (int k = 0; k < 12; ++k) dv1[k] = __builtin_nontemporal_load(p1 + k);
        }

        // ---- u gathers for both elements (8 independent loads) ----
        float eu0[4][3], eu1[4][3];
        if (use_ut) {
            const int* nd0p = (const int*)&nd0;
            const int* nd1p = (const int*)&nd1;
            #pragma unroll
            for (int n = 0; n < 4; ++n) {
                const float4 a4 = ut[(size_t)nd0p[n] * 4 + b];
                eu0[n][0] = a4.x; eu0[n][1] = a4.y; eu0[n][2] = a4.z;
            }
            #pragma unroll
            for (int n = 0; n < 4; ++n) {
                const float4 a4 = ut[(size_t)nd1p[n] * 4 + b];
                eu1[n][0] = a4.x; eu1[n][1] = a4.y; eu1[n][2] = a4.z;
            }
        } else {
            const float* ub = u + (size_t)b * n_nodes * 3;
            const int* nd0p = (const int*)&nd0;
            const int* nd1p = (const int*)&nd1;
            #pragma unroll
            for (int n = 0; n < 4; ++n) {
                const float* pp = ub + (size_t)nd0p[n] * 3;
                eu0[n][0] = pp[0]; eu0[n][1] = pp[1]; eu0[n][2] = pp[2];
            }
            #pragma unroll
            for (int n = 0; n < 4; ++n) {
                const float* pp = ub + (size_t)nd1p[n] * 3;
                eu1[n][0] = pp[0]; eu1[n][1] = pp[1]; eu1[n][2] = pp[2];
            }
        }

        const float4 w4 = *reinterpret_cast<const float4*>(qw);
        const float wq0[4] = {dj0.x * w4.x, dj0.y * w4.y, dj0.z * w4.z, dj0.w * w4.w};
        const float wq1[4] = {dj1.x * w4.x, dj1.y * w4.y, dj1.z * w4.z, dj1.w * w4.w};

        acc = nh_energy_elem(dv0, eu0, wq0);
        if (v1) acc += nh_energy_elem(dv1, eu1, wq1);
    }

    // reduce across lanes with the same b (stride-4 groups): offsets 32..4
    #pragma unroll
    for (int off = 32; off >= 4; off >>= 1)
        acc += __shfl_down(acc, off);
    // lanes 0..3 now hold this wave's batch sums

    __shared__ float s_red[4][4];
    const int lane = t & 63;
    const int wid  = t >> 6;
    if (lane < 4) s_red[wid][lane] = acc;
    __syncthreads();
    if (t < 4)
        partial[(size_t)blockIdx.x * 4 + t] =
            (s_red[0][t] + s_red[1][t]) + (s_red[2][t] + s_red[3][t]);
}

__global__ __launch_bounds__(256) void nh_final(
    const float* __restrict__ partial,  // (nparts, 4)
    float* __restrict__ out,            // (4,)
    int nparts)
{
    float accb[4] = {0.f, 0.f, 0.f, 0.f};
    for (int i = threadIdx.x; i < nparts; i += 256) {
        const float4 p = reinterpret_cast<const float4*>(partial)[i];
        accb[0] += p.x; accb[1] += p.y; accb[2] += p.z; accb[3] += p.w;
    }

    #pragma unroll
    for (int b = 0; b < 4; ++b) {
        float v = accb[b];
        #pragma unroll
        for (int off = 32; off > 0; off >>= 1)
            v += __shfl_down(v, off);
        accb[b] = v;
    }

    __shared__ float lds[4][4];
    const int lane = threadIdx.x & 63;
    const int wid  = threadIdx.x >> 6;
    if (lane == 0) {
        #pragma unroll
        for (int b = 0; b < 4; ++b) lds[wid][b] = accb[b];
    }
    __syncthreads();
    if (threadIdx.x == 0) {
        #pragma unroll
        for (int b = 0; b < 4; ++b)
            out[b] = (lds[0][b] + lds[1][b]) + (lds[2][b] + lds[3][b]);
    }
}

extern "C" void kernel_launch(void* const* d_in, const int* in_sizes, int n_in,
                              void* d_out, int out_size, void* d_ws, size_t ws_size,
                              hipStream_t stream) {
    const float* u        = (const float*)d_in[0];
    const int*   elements = (const int*)d_in[1];
    const float* dN_dx    = (const float*)d_in[2];
    const float* detJ     = (const float*)d_in[3];
    const float* qw       = (const float*)d_in[4];
    float* out = (float*)d_out;

    const int B       = out_size;            // 4
    const int n_nodes = in_sizes[0] / (3 * B);
    const int n_elem  = in_sizes[1] / 4;

    const int threads = 256;
    const int nblocks = (n_elem + EPB - 1) / EPB;

    const size_t ut_bytes      = (size_t)n_nodes * 4 * sizeof(float4);  // padded
    const size_t partial_bytes = (size_t)nblocks * 4 * sizeof(float);
    const int use_ut = (ws_size >= ut_bytes + partial_bytes) ? 1 : 0;

    float4* ut     = (float4*)d_ws;
    float* partial = use_ut ? (float*)((char*)d_ws + ut_bytes) : (float*)d_ws;

    if (use_ut) {
        const int tb = (n_nodes + threads - 1) / threads;
        nh_transpose_u_pad<<<tb, threads, 0, stream>>>(u, ut, n_nodes);
    }

    nh_partial_v5<<<nblocks, threads, 0, stream>>>(u, ut, elements, dN_dx, detJ, qw,
                                                   partial, n_elem, n_nodes, use_ut);
    nh_final<<<1, threads, 0, stream>>>(partial, out, nblocks);
}

// Round 7
// 57.956 us; speedup vs baseline: 1.7902x; 1.5623x over previous
//
#include <hip/hip_runtime.h>

// Neo-Hookean constants (match reference)
#define MU_C   3846.1538461538462f   // E/(2(1+nu))
#define LM_C   5769.2307692307695f   // E*nu/((1+nu)(1-2nu))
#define LOGC   (MU_C + 0.5f * LM_C)  // combined log coefficient
#define EPS_C  1e-10f

// B=4, N_QUAD=4, NPE=4 fixed by the reference problem.
// v6: thread = (element, batch), K=4 elements per thread, register-level
// software pipeline with 2 slots (compute slot s while slot s^1 loads fly).
#define KPT 4            // elements per thread
#define TILE (64 * KPT)  // elements per block (64 pairs/iter * K iters)

// Transpose u (B, n_nodes, 3) -> ut (n_nodes, B, 4) padded float4 (64B/node).
__global__ __launch_bounds__(256) void nh_transpose_u_pad(
    const float* __restrict__ u, float4* __restrict__ ut, int n_nodes)
{
    const int i = blockIdx.x * 256 + threadIdx.x;
    if (i >= n_nodes) return;
    float4* q = ut + (size_t)i * 4;
    #pragma unroll
    for (int b = 0; b < 4; ++b) {
        const float* p = u + ((size_t)b * n_nodes + i) * 3;
        q[b] = make_float4(p[0], p[1], p[2], 0.f);
    }
}

// energy of one element/batch from its register state
__device__ __forceinline__ float nh_energy(
    const float4* dn,      // 12 float4 = 48-float dN slab, d[(q*4+n)*3+j]
    const float4* uu,      // 4 float4 node displacements (xyz used)
    const float*  wqv)     // detJ*qw per quad point (0 if invalid elem)
{
    const float* d  = reinterpret_cast<const float*>(dn);
    const float* us = reinterpret_cast<const float*>(uu);
    float a = 0.f;
    #pragma unroll
    for (int q = 0; q < 4; ++q) {
        float F[3][3];
        #pragma unroll
        for (int i = 0; i < 3; ++i) {
            #pragma unroll
            for (int j = 0; j < 3; ++j) {
                float g = 0.f;
                #pragma unroll
                for (int n = 0; n < 4; ++n)
                    g = fmaf(us[n * 4 + i], d[(q*4 + n)*3 + j], g);
                F[i][j] = g + ((i == j) ? 1.f : 0.f);
            }
        }
        const float J =
              F[0][0] * (F[1][1]*F[2][2] - F[1][2]*F[2][1])
            - F[0][1] * (F[1][0]*F[2][2] - F[1][2]*F[2][0])
            + F[0][2] * (F[1][0]*F[2][1] - F[1][1]*F[2][0]);
        float IC = 0.f;
        #pragma unroll
        for (int i = 0; i < 3; ++i)
            #pragma unroll
            for (int j = 0; j < 3; ++j)
                IC = fmaf(F[i][j], F[i][j], IC);
        const float lj = __logf(fmaxf(J, EPS_C));
        const float W = 0.5f * MU_C * (IC - 3.f)
                      + 0.25f * LM_C * fmaf(J, J, -1.f)
                      - LOGC * lj;
        a = fmaf(W, wqv[q], a);
    }
    return a;
}

__global__ __launch_bounds__(256) void nh_partial_v6(
    const float4* __restrict__ ut,        // (n_nodes, 4) padded float4
    const int*    __restrict__ elements,  // (n_elem, 4)
    const float*  __restrict__ dN_dx,     // (n_elem, 4, 4, 3)
    const float*  __restrict__ detJ,      // (n_elem, 4)
    const float*  __restrict__ qw,        // (4,)
    float* __restrict__ partial,          // (gridDim.x, 4)
    int n_elem)
{
    const int t = threadIdx.x;
    const int b = t & 3;
    const int p = t >> 2;                       // pair index: 64 per block
    const int base = blockIdx.x * TILE + p;     // element for m: base + m*64

    const int4*   elp = reinterpret_cast<const int4*>(elements);
    const float4* djp = reinterpret_cast<const float4*>(detJ);
    const float4* dnp = reinterpret_cast<const float4*>(dN_dx);
    const float4  w4  = *reinterpret_cast<const float4*>(qw);

    // two pipeline slots, all compile-time indexed (full unroll below)
    int4   nd[2];
    float4 dj[2];
    float4 dn[2][12];
    float4 uu[2][4];
    float  wqv[2][4];

    // ---- slot load: issue element-indexed loads, then gathers ----
    #define NH_LOAD(S, M)                                                     \
    {                                                                         \
        const int e  = base + (M) * 64;                                       \
        const int ec = min(e, n_elem - 1);                                    \
        const bool valid = (e < n_elem);                                      \
        nd[S] = elp[ec];                                                      \
        dj[S] = djp[ec];                                                      \
        const float4* dptr = dnp + (size_t)ec * 12;                           \
        _Pragma("unroll")                                                     \
        for (int k = 0; k < 12; ++k) dn[S][k] = dptr[k];                      \
        const int* ndp = reinterpret_cast<const int*>(&nd[S]);                \
        _Pragma("unroll")                                                     \
        for (int n = 0; n < 4; ++n)                                           \
            uu[S][n] = ut[(size_t)ndp[n] * 4 + b];                            \
        const float vs = valid ? 1.f : 0.f;                                   \
        wqv[S][0] = dj[S].x * w4.x * vs;                                      \
        wqv[S][1] = dj[S].y * w4.y * vs;                                      \
        wqv[S][2] = dj[S].z * w4.z * vs;                                      \
        wqv[S][3] = dj[S].w * w4.w * vs;                                      \
    }

    float acc = 0.f;

    // prologue: fill both slots
    NH_LOAD(0, 0)
    NH_LOAD(1, 1)

    // steady state: compute slot (m&1), then refill it for m+2
    #pragma unroll
    for (int m = 0; m < KPT; ++m) {
        const int s = m & 1;
        acc += nh_energy(dn[s], uu[s], wqv[s]);
        if (m + 2 < KPT) {
            if (s == 0) { NH_LOAD(0, m + 2) } else { NH_LOAD(1, m + 2) }
        }
    }
    #undef NH_LOAD

    // reduce across lanes with the same b (stride-4 groups): offsets 32..4
    #pragma unroll
    for (int off = 32; off >= 4; off >>= 1)
        acc += __shfl_down(acc, off);
    // lanes 0..3 now hold this wave's batch sums

    __shared__ float s_red[4][4];
    const int lane = t & 63;
    const int wid  = t >> 6;
    if (lane < 4) s_red[wid][lane] = acc;
    __syncthreads();
    if (t < 4)
        partial[(size_t)blockIdx.x * 4 + t] =
            (s_red[0][t] + s_red[1][t]) + (s_red[2][t] + s_red[3][t]);
}

__global__ __launch_bounds__(256) void nh_final(
    const float* __restrict__ partial,  // (nparts, 4)
    float* __restrict__ out,            // (4,)
    int nparts)
{
    float accb[4] = {0.f, 0.f, 0.f, 0.f};
    for (int i = threadIdx.x; i < nparts; i += 256) {
        const float4 p = reinterpret_cast<const float4*>(partial)[i];
        accb[0] += p.x; accb[1] += p.y; accb[2] += p.z; accb[3] += p.w;
    }

    #pragma unroll
    for (int b = 0; b < 4; ++b) {
        float v = accb[b];
        #pragma unroll
        for (int off = 32; off > 0; off >>= 1)
            v += __shfl_down(v, off);
        accb[b] = v;
    }

    __shared__ float lds[4][4];
    const int lane = threadIdx.x & 63;
    const int wid  = threadIdx.x >> 6;
    if (lane == 0) {
        #pragma unroll
        for (int b = 0; b < 4; ++b) lds[wid][b] = accb[b];
    }
    __syncthreads();
    if (threadIdx.x == 0) {
        #pragma unroll
        for (int b = 0; b < 4; ++b)
            out[b] = (lds[0][b] + lds[1][b]) + (lds[2][b] + lds[3][b]);
    }
}

extern "C" void kernel_launch(void* const* d_in, const int* in_sizes, int n_in,
                              void* d_out, int out_size, void* d_ws, size_t ws_size,
                              hipStream_t stream) {
    const float* u        = (const float*)d_in[0];
    const int*   elements = (const int*)d_in[1];
    const float* dN_dx    = (const float*)d_in[2];
    const float* detJ     = (const float*)d_in[3];
    const float* qw       = (const float*)d_in[4];
    float* out = (float*)d_out;

    const int B       = out_size;            // 4
    const int n_nodes = in_sizes[0] / (3 * B);
    const int n_elem  = in_sizes[1] / 4;

    const int threads = 256;
    const int nblocks = (n_elem + TILE - 1) / TILE;

    const size_t ut_bytes      = (size_t)n_nodes * 4 * sizeof(float4);  // padded
    float4* ut     = (float4*)d_ws;
    float* partial = (float*)((char*)d_ws + ut_bytes);

    const int tb = (n_nodes + threads - 1) / threads;
    nh_transpose_u_pad<<<tb, threads, 0, stream>>>(u, ut, n_nodes);

    nh_partial_v6<<<nblocks, threads, 0, stream>>>(ut, elements, dN_dx, detJ, qw,
                                                   partial, n_elem);
    nh_final<<<1, threads, 0, stream>>>(partial, out, nblocks);
}